// Round 11
// baseline (193.681 us; speedup 1.0000x reference)
//
#include <hip/hip_runtime.h>
#include <cmath>

#define S_TOT 4096
#define CIN   256
#define HID   512
#define NHEAD 8
#define DIMH  64

typedef __attribute__((ext_vector_type(8))) short bf16x8;
typedef __attribute__((ext_vector_type(4))) float f32x4;
typedef __attribute__((ext_vector_type(16))) float f32x16;
typedef __attribute__((address_space(1))) const void gv_t;
typedef __attribute__((address_space(3))) void lv_t;

__device__ __forceinline__ ushort f2bf(float f) {
    union { float f; unsigned u; } v; v.f = f;
    unsigned r = (v.u + 0x7FFFu + ((v.u >> 16) & 1u)) >> 16;
    return (ushort)r;
}

__device__ __forceinline__ float bf2f(ushort u) {
    union { unsigned u; float f; } v; v.u = ((unsigned)u) << 16; return v.f;
}

__device__ __forceinline__ float exp2_fast(float x) {
    float r; asm("v_exp_f32 %0, %1" : "=v"(r) : "v"(x)); return r;
}

__device__ __forceinline__ unsigned cvt_pk_bf16(float lo, float hi) {
    unsigned r; asm("v_cvt_pk_bf16_f32 %0, %1, %2" : "=v"(r) : "v"(lo), "v"(hi)); return r;
}

// 0.125 (1/sqrt(64)) * log2(e): folds softmax base-2 conversion into Q.
#define QSCALE 0.18033688011112042f

// ---------------------------------------------------------------------------
// Fused prologue: w_qkv cast (blocks 0..383), w_out cast (384..511),
// x transpose-cast (512..1023).
// ---------------------------------------------------------------------------
__global__ __launch_bounds__(256)
void prologue_kernel(const float* __restrict__ w_qkv, const float* __restrict__ w_out,
                     const float* __restrict__ x, ushort* __restrict__ wqb,
                     ushort* __restrict__ wob, ushort* __restrict__ xt) {
    __shared__ float tb[64][65];
    const int bid = blockIdx.x, t = threadIdx.x;
    if (bid < 512) {
        const float* src = (bid < 384) ? w_qkv : w_out;
        ushort* dst = (bid < 384) ? wqb : wob;
        const long i = ((long)(bid < 384 ? bid : bid - 384) * 256 + t) * 4;
        float4 v = *(const float4*)&src[i];
        ushort4 p;
        p.x = f2bf(v.x); p.y = f2bf(v.y); p.z = f2bf(v.z); p.w = f2bf(v.w);
        *(ushort4*)&dst[i] = p;
        return;
    }
    const int xb_ = bid - 512;              // [0,512): (s0/64) + 64*(c0/64 + 4*z)
    const int sx = xb_ & 63, rest = xb_ >> 6;
    const int cy = rest & 3, cz = rest >> 2;
    const int s0 = sx * 64, c0 = cy * 64;
    const long xb = (long)cz * CIN * S_TOT;
    #pragma unroll
    for (int i = 0; i < 16; ++i) {
        int idx = t + i * 256;
        int c = idx >> 6, s = idx & 63;
        tb[c][s] = x[xb + (long)(c0 + c) * S_TOT + s0 + s];
    }
    __syncthreads();
    const long ob = (long)cz * S_TOT * CIN;
    const int s = t >> 2, cq = (t & 3) * 16;
    #pragma unroll
    for (int j = 0; j < 4; ++j) {
        ushort4 pk;
        pk.x = f2bf(tb[cq + j * 4 + 0][s]);
        pk.y = f2bf(tb[cq + j * 4 + 1][s]);
        pk.z = f2bf(tb[cq + j * 4 + 2][s]);
        pk.w = f2bf(tb[cq + j * 4 + 3][s]);
        *(ushort4*)&xt[ob + (long)(s0 + s) * CIN + c0 + cq + j * 4] = pk;
    }
}

// ---------------------------------------------------------------------------
// bf16 MFMA GEMM (16x16x32).
// MODE 0: A=xt, B=w_qkv[0:1024] -> q (pre-scaled by QSCALE) / k, [bh][s][64]
// MODE 1: A=w_qkv[1024:1536], B=xt -> v [bh][d][s'] with key bits 2<->3
//         swapped within each 16-key group (matches attention's register-P).
// MODE 2: A=w_out, B=attn-bf16 -> out [b][o][s] fp32 + bias
// ---------------------------------------------------------------------------
template<int MODE>
__global__ __launch_bounds__(256)
void gemm_mfma_kernel(const ushort* __restrict__ Ag, const ushort* __restrict__ Bg,
                      void* __restrict__ outp, const float* __restrict__ bias,
                      int Kdim, long strideA, long strideB) {
    __shared__ __attribute__((aligned(16))) ushort Abuf[128 * 64];
    __shared__ __attribute__((aligned(16))) ushort Bbuf[128 * 64];
    const int t = threadIdx.x, lane = t & 63;
    const int l15 = lane & 15, g = lane >> 4;
    const int wid = t >> 6, wr = wid >> 1, wc = wid & 1;
    const int bz = blockIdx.z;
    const int am0 = blockIdx.y * 128, bn0 = blockIdx.x * 128;
    Ag += (long)bz * strideA;
    Bg += (long)bz * strideB;

    f32x4 acc[4][4];
    #pragma unroll
    for (int i = 0; i < 4; ++i)
        #pragma unroll
        for (int j = 0; j < 4; ++j)
            acc[i][j] = (f32x4){0.f, 0.f, 0.f, 0.f};

    for (int k0 = 0; k0 < Kdim; k0 += 64) {
        __syncthreads();
        #pragma unroll
        for (int i = 0; i < 4; ++i) {
            const int chunk = t + i * 256;
            const int row = chunk >> 3, sl = chunk & 7;
            const ushort* srcA = Ag + (long)(am0 + row) * Kdim + k0 + ((sl ^ (row & 7)) << 3);
            __builtin_amdgcn_global_load_lds((gv_t*)srcA,
                (lv_t*)((char*)Abuf + (i * 256 + (t & ~63)) * 16), 16, 0, 0);
            const ushort* srcB = Bg + (long)(bn0 + row) * Kdim + k0 + ((sl ^ (row & 7)) << 3);
            __builtin_amdgcn_global_load_lds((gv_t*)srcB,
                (lv_t*)((char*)Bbuf + (i * 256 + (t & ~63)) * 16), 16, 0, 0);
        }
        asm volatile("s_waitcnt vmcnt(0)" ::: "memory");
        __syncthreads();

        bf16x8 bfr[4][2];
        #pragma unroll
        for (int fn = 0; fn < 4; ++fn) {
            const int row = wc * 64 + fn * 16 + l15;
            #pragma unroll
            for (int hf = 0; hf < 2; ++hf)
                bfr[fn][hf] = *(const bf16x8*)((const char*)Bbuf + row * 128
                                + (((hf * 4 + g) ^ (row & 7)) << 4));
        }
        #pragma unroll
        for (int fm = 0; fm < 4; ++fm) {
            const int row = wr * 64 + fm * 16 + l15;
            const bf16x8 a0 = *(const bf16x8*)((const char*)Abuf + row * 128
                                + (((g) ^ (row & 7)) << 4));
            const bf16x8 a1 = *(const bf16x8*)((const char*)Abuf + row * 128
                                + (((4 + g) ^ (row & 7)) << 4));
            #pragma unroll
            for (int fn = 0; fn < 4; ++fn) {
                acc[fm][fn] = __builtin_amdgcn_mfma_f32_16x16x32_bf16(a0, bfr[fn][0], acc[fm][fn], 0, 0, 0);
                acc[fm][fn] = __builtin_amdgcn_mfma_f32_16x16x32_bf16(a1, bfr[fn][1], acc[fm][fn], 0, 0, 0);
            }
        }
    }

    #pragma unroll
    for (int fm = 0; fm < 4; ++fm)
        #pragma unroll
        for (int fn = 0; fn < 4; ++fn)
            #pragma unroll
            for (int r = 0; r < 4; ++r) {
                const int ar = am0 + wr * 64 + fm * 16 + g * 4 + r;
                const int bc = bn0 + wc * 64 + fn * 16 + l15;
                if (MODE == 0) {
                    const int which = bc >> 9, h = (bc >> 6) & 7, d = bc & 63;
                    const float scl = (which == 0) ? QSCALE : 1.0f;
                    ushort* O = (ushort*)outp;
                    O[(long)which * 4194304 + (((long)(bz * NHEAD + h)) * S_TOT + ar) * DIMH + d]
                        = f2bf(acc[fm][fn][r] * scl);
                } else if (MODE == 1) {
                    const int h = ar >> 6, d = ar & 63;
                    const int jm = bc & 15;
                    const int pjm = (jm & 3) | ((jm & 4) << 1) | ((jm & 8) >> 1);
                    const int pc = (bc & ~15) | pjm;
                    ushort* O = (ushort*)outp;
                    O[(((long)(bz * NHEAD + h)) * DIMH + d) * S_TOT + pc] = f2bf(acc[fm][fn][r]);
                } else {
                    float* O = (float*)outp;
                    O[((long)bz * CIN + ar) * S_TOT + bc] = acc[fm][fn][r] + bias[ar];
                }
            }
}

// ---------------------------------------------------------------------------
// Flash attention, 32x32x16, key-split x SP (NT = tiles per split).
// Round-9-verified mappings + conflict-free swizzle. New: per-q softmax sums
// collected by 4 ones-B MFMAs into lacc (rows = per-q sums over all 64 keys,
// K-dim spans both lane halves) -> no per-lane adds, no epilogue shuffles.
// Overflow guard every 8 tiles (threshold 2^64, rescale 2^-48).
// Grid z = sp*2 + b.
// ---------------------------------------------------------------------------
template<int NT>
__global__ __launch_bounds__(256, 4)
void attn_mfma_kernel(const ushort* __restrict__ qg, const ushort* __restrict__ kg,
                      const ushort* __restrict__ vg, ushort* __restrict__ pout,
                      float2* __restrict__ mlout) {
    __shared__ __attribute__((aligned(16))) ushort kbuf[2][64 * 64];
    __shared__ __attribute__((aligned(16))) ushort vbuf[2][64 * 64];

    const int t = threadIdx.x;
    const int lane = t & 63, wid = t >> 6;          // wid 0..3
    const int l31 = lane & 31, h = lane >> 5;
    const int head = blockIdx.y;
    const int sp = blockIdx.z >> 1, b = blockIdx.z & 1;
    const int bh = b * NHEAD + head;
    const int qrow0 = blockIdx.x * 128 + wid * 32;
    const long kbase = (long)sp * (NT * 64);

    const int sw_lo = (l31 ^ (l31 >> 3)) & 7;
    const int sw_hi = sw_lo ^ 4;

    // Q B-fragments: col q = l31, k(d) = ds*16 + 8h + j  (pre-scaled)
    const ushort* qp = qg + ((long)bh * S_TOT + qrow0 + l31) * DIMH + h * 8;
    bf16x8 qfr[4];
    #pragma unroll
    for (int ds = 0; ds < 4; ++ds) qfr[ds] = *(const bf16x8*)(qp + ds * 16);

    const short ONE = (short)0x3F80;
    const bf16x8 ones = {ONE, ONE, ONE, ONE, ONE, ONE, ONE, ONE};

    f32x16 oacc0 = {}, oacc1 = {}, lacc = {};
    f32x16 bias16 = {};                 // -(accumulated rescale) broadcast
    float nmr = 0.f;

    const long kg_base = (long)bh * S_TOT * DIMH;
    const long vg_base = (long)bh * DIMH * S_TOT;
    const int sl = lane & 7, sr = lane >> 3;

    auto STAGE = [&](int buf, long key0) {
        #pragma unroll
        for (int c = 0; c < 2; ++c) {
            const int row = wid * 16 + c * 8 + sr;          // row>>3 = wid*2+c
            const int sz = (sl ^ sr ^ (wid * 2 + c)) & 7;   // src chunk for slot sl
            char* kdst = (char*)(&kbuf[buf][0]) + wid * 2048 + c * 1024;
            char* vdst = (char*)(&vbuf[buf][0]) + wid * 2048 + c * 1024;
            const char* srcK = (const char*)(kg + kg_base + (key0 + row) * DIMH) + (sz << 4);
            __builtin_amdgcn_global_load_lds((gv_t*)srcK, (lv_t*)kdst, 16, 0, 0);
            const char* srcV = (const char*)(vg + vg_base + (long)row * S_TOT + key0) + (sz << 4);
            __builtin_amdgcn_global_load_lds((gv_t*)srcV, (lv_t*)vdst, 16, 0, 0);
        }
    };

    STAGE(0, kbase);
    asm volatile("s_waitcnt vmcnt(0)" ::: "memory");
    __syncthreads();

    for (int kt0 = 0; kt0 < NT; ++kt0) {
        const int cur = kt0 & 1;
        if (kt0 + 1 < NT) STAGE(cur ^ 1, kbase + (long)(kt0 + 1) * 64);

        const char* kb_ = (const char*)(&kbuf[cur][0]);
        const char* vb_ = (const char*)(&vbuf[cur][0]);

        // --- S^T = K Q^T + bias: lane q=l31; key = 32kg + (r&3)+8(r>>2)+4h
        f32x16 s0, s1;
        __builtin_amdgcn_s_setprio(1);
        {
            const bf16x8 kf0 = *(const bf16x8*)(kb_ + l31 * 128 + ((h ^ sw_lo) << 4));
            const bf16x8 kf1 = *(const bf16x8*)(kb_ + 4096 + l31 * 128 + ((h ^ sw_hi) << 4));
            s0 = __builtin_amdgcn_mfma_f32_32x32x16_bf16(kf0, qfr[0], bias16, 0, 0, 0);
            s1 = __builtin_amdgcn_mfma_f32_32x32x16_bf16(kf1, qfr[0], bias16, 0, 0, 0);
        }
        #pragma unroll
        for (int ds = 1; ds < 4; ++ds) {
            const bf16x8 kf0 = *(const bf16x8*)(kb_ + l31 * 128 + (((2 * ds + h) ^ sw_lo) << 4));
            const bf16x8 kf1 = *(const bf16x8*)(kb_ + 4096 + l31 * 128 + (((2 * ds + h) ^ sw_hi) << 4));
            s0 = __builtin_amdgcn_mfma_f32_32x32x16_bf16(kf0, qfr[ds], s0, 0, 0, 0);
            s1 = __builtin_amdgcn_mfma_f32_32x32x16_bf16(kf1, qfr[ds], s1, 0, 0, 0);
        }
        __builtin_amdgcn_s_setprio(0);

        // --- exp + pack P directly (V key order pre-swapped in global) ---
        bf16x8 pf0, pf1, pf2, pf3;
        {
            float e[16];
            #pragma unroll
            for (int r = 0; r < 16; ++r) e[r] = exp2_fast(s0[r]);
            union { unsigned u[4]; bf16x8 v; } A_, B_;
            #pragma unroll
            for (int w = 0; w < 4; ++w) A_.u[w] = cvt_pk_bf16(e[2 * w], e[2 * w + 1]);
            #pragma unroll
            for (int w = 0; w < 4; ++w) B_.u[w] = cvt_pk_bf16(e[8 + 2 * w], e[9 + 2 * w]);
            pf0 = A_.v; pf1 = B_.v;
        }
        {
            float e[16];
            #pragma unroll
            for (int r = 0; r < 16; ++r) e[r] = exp2_fast(s1[r]);
            union { unsigned u[4]; bf16x8 v; } A_, B_;
            #pragma unroll
            for (int w = 0; w < 4; ++w) A_.u[w] = cvt_pk_bf16(e[2 * w], e[2 * w + 1]);
            #pragma unroll
            for (int w = 0; w < 4; ++w) B_.u[w] = cvt_pk_bf16(e[8 + 2 * w], e[9 + 2 * w]);
            pf2 = A_.v; pf3 = B_.v;
        }

        // --- O += P V; lsum += P * ones ---
        __builtin_amdgcn_s_setprio(1);
        {
            const bf16x8 vf00 = *(const bf16x8*)(vb_ + l31 * 128 + ((h ^ sw_lo) << 4));
            const bf16x8 vf01 = *(const bf16x8*)(vb_ + 4096 + l31 * 128 + ((h ^ sw_hi) << 4));
            oacc0 = __builtin_amdgcn_mfma_f32_32x32x16_bf16(pf0, vf00, oacc0, 0, 0, 0);
            oacc1 = __builtin_amdgcn_mfma_f32_32x32x16_bf16(pf0, vf01, oacc1, 0, 0, 0);
            lacc  = __builtin_amdgcn_mfma_f32_32x32x16_bf16(pf0, ones, lacc, 0, 0, 0);
            const bf16x8 vf10 = *(const bf16x8*)(vb_ + l31 * 128 + (((2 + h) ^ sw_lo) << 4));
            const bf16x8 vf11 = *(const bf16x8*)(vb_ + 4096 + l31 * 128 + (((2 + h) ^ sw_hi) << 4));
            oacc0 = __builtin_amdgcn_mfma_f32_32x32x16_bf16(pf1, vf10, oacc0, 0, 0, 0);
            oacc1 = __builtin_amdgcn_mfma_f32_32x32x16_bf16(pf1, vf11, oacc1, 0, 0, 0);
            lacc  = __builtin_amdgcn_mfma_f32_32x32x16_bf16(pf1, ones, lacc, 0, 0, 0);
            const bf16x8 vf20 = *(const bf16x8*)(vb_ + l31 * 128 + (((4 + h) ^ sw_lo) << 4));
            const bf16x8 vf21 = *(const bf16x8*)(vb_ + 4096 + l31 * 128 + (((4 + h) ^ sw_hi) << 4));
            oacc0 = __builtin_amdgcn_mfma_f32_32x32x16_bf16(pf2, vf20, oacc0, 0, 0, 0);
            oacc1 = __builtin_amdgcn_mfma_f32_32x32x16_bf16(pf2, vf21, oacc1, 0, 0, 0);
            lacc  = __builtin_amdgcn_mfma_f32_32x32x16_bf16(pf2, ones, lacc, 0, 0, 0);
            const bf16x8 vf30 = *(const bf16x8*)(vb_ + l31 * 128 + (((6 + h) ^ sw_lo) << 4));
            const bf16x8 vf31 = *(const bf16x8*)(vb_ + 4096 + l31 * 128 + (((6 + h) ^ sw_hi) << 4));
            oacc0 = __builtin_amdgcn_mfma_f32_32x32x16_bf16(pf3, vf30, oacc0, 0, 0, 0);
            oacc1 = __builtin_amdgcn_mfma_f32_32x32x16_bf16(pf3, vf31, oacc1, 0, 0, 0);
            lacc  = __builtin_amdgcn_mfma_f32_32x32x16_bf16(pf3, ones, lacc, 0, 0, 0);
        }
        __builtin_amdgcn_s_setprio(0);

        // --- rare overflow guard, checked every 8 tiles ---
        if ((kt0 & 7) == 7) {
            float mx = lacc[0];
            #pragma unroll
            for (int r = 1; r < 16; ++r) mx = fmaxf(mx, lacc[r]);
            if (__any(mx > 1.8446744e19f)) {          // 2^64
                const float sc = 3.5527136788e-15f;   // 2^-48
                #pragma unroll
                for (int r = 0; r < 16; ++r) {
                    oacc0[r] *= sc; oacc1[r] *= sc; lacc[r] *= sc;
                }
                nmr -= 48.0f;
                #pragma unroll
                for (int r = 0; r < 16; ++r) bias16[r] = nmr;
            }
        }

        asm volatile("s_waitcnt vmcnt(0)" ::: "memory");
        __syncthreads();
    }

    // epilogue: unnormalized partial O (bf16) + per-q (m, l) fp32 (no shuffles)
    const long pbase = (((long)sp * 2 + b) * S_TOT) * HID;
    #pragma unroll
    for (int r = 0; r < 16; ++r) {
        const int q = (r & 3) + 8 * (r >> 2) + 4 * h;
        const long off = pbase + (long)(qrow0 + q) * HID + head * 64 + l31;
        pout[off]      = f2bf(oacc0[r]);
        pout[off + 32] = f2bf(oacc1[r]);
    }
    if (l31 == 0) {
        float2* mlp = mlout + ((long)sp * 2 * NHEAD * S_TOT) + (long)bh * S_TOT + qrow0;
        #pragma unroll
        for (int r = 0; r < 16; ++r) {
            const int q = (r & 3) + 8 * (r >> 2) + 4 * h;
            mlp[q] = make_float2(-nmr, lacc[r]);
        }
    }
}

// ---------------------------------------------------------------------------
// Merge SP key-split partials: out = sum_i w_i*O_i / sum_i w_i*l_i,
// w_i = 2^(m_i - max m). One thread = 8 hd of one (b,q).
// ---------------------------------------------------------------------------
template<int SP>
__global__ __launch_bounds__(256)
void attn_merge_kernel(const ushort* __restrict__ part, const float2* __restrict__ ml,
                       ushort* __restrict__ aout) {
    const long i = (long)blockIdx.x * 256 + threadIdx.x;   // [0, 2*4096*64)
    const int hd8 = (int)(i & 63);
    const long bq = i >> 6;
    const int q = (int)(bq & (S_TOT - 1)), b = (int)(bq >> 12);
    const int h = hd8 >> 3;
    const long mlsp = (long)2 * NHEAD * S_TOT;
    const long mlidx = (long)(b * NHEAD + h) * S_TOT + q;
    float2 mls[SP];
    float m = -3e38f;
    #pragma unroll
    for (int sp = 0; sp < SP; ++sp) {
        mls[sp] = ml[sp * mlsp + mlidx];
        m = fmaxf(m, mls[sp].x);
    }
    float w[SP];
    float wsum = 0.f;
    #pragma unroll
    for (int sp = 0; sp < SP; ++sp) {
        w[sp] = exp2_fast(mls[sp].x - m);
        wsum += w[sp] * mls[sp].y;
    }
    const float inv = 1.0f / wsum;
    const long psp = (long)2 * S_TOT * HID;
    const long off = ((long)b * S_TOT + q) * HID + hd8 * 8;
    float acc[8] = {};
    #pragma unroll
    for (int sp = 0; sp < SP; ++sp) {
        const bf16x8 p = *(const bf16x8*)&part[sp * psp + off];
        #pragma unroll
        for (int j = 0; j < 8; ++j) acc[j] += w[sp] * bf2f((ushort)p[j]);
    }
    union { ushort u[8]; bf16x8 v; } o;
    #pragma unroll
    for (int j = 0; j < 8; ++j) o.u[j] = f2bf(acc[j] * inv);
    *(bf16x8*)&aout[off] = o.v;
}

// ---------------------------------------------------------------------------
extern "C" void kernel_launch(void* const* d_in, const int* in_sizes, int n_in,
                              void* d_out, int out_size, void* d_ws, size_t ws_size,
                              hipStream_t stream) {
    const float* x     = (const float*)d_in[0];
    const float* w_qkv = (const float*)d_in[1];
    const float* w_out = (const float*)d_in[2];
    const float* b_out = (const float*)d_in[3];
    float* out = (float*)d_out;

    const long PERQKV = (long)2 * NHEAD * S_TOT * DIMH;   // 4,194,304
    ushort* qws = (ushort*)d_ws;
    ushort* kws = qws + PERQKV;
    ushort* vws = kws + PERQKV;
    ushort* xt  = vws + PERQKV;                           // 2*4096*256
    ushort* wqb = xt + (long)2 * S_TOT * CIN;             // 1536*256
    ushort* wob = wqb + (long)3 * HID * CIN;              // 256*512
    ushort* awb = wob + (long)CIN * HID;                  // 2*4096*512
    ushort* prt = awb + (long)2 * S_TOT * HID;            // SP * 2*4096*512

    // split count: 4 if workspace permits (74.5 MB), else 2 (55.7 MB, proven)
    const long base_us = 3 * PERQKV + (long)2 * S_TOT * CIN + (long)3 * HID * CIN
                       + (long)CIN * HID + (long)2 * S_TOT * HID;
    const long need4 = (base_us + 4L * 2 * S_TOT * HID) * 2 + 4L * 2 * NHEAD * S_TOT * 8;
    const int SP = (ws_size >= (size_t)need4) ? 4 : 2;
    float2* mlw = (float2*)(prt + (long)SP * 2 * S_TOT * HID);

    prologue_kernel<<<dim3(1024), 256, 0, stream>>>(w_qkv, w_out, x, wqb, wob, xt);

    gemm_mfma_kernel<0><<<dim3(1024 / 128, S_TOT / 128, 2), 256, 0, stream>>>(
        xt, wqb, qws, nullptr, CIN, (long)S_TOT * CIN, 0L);
    gemm_mfma_kernel<1><<<dim3(S_TOT / 128, 512 / 128, 2), 256, 0, stream>>>(
        wqb + (long)1024 * CIN, xt, vws, nullptr, CIN, 0L, (long)S_TOT * CIN);

    if (SP == 4) {
        attn_mfma_kernel<16><<<dim3(S_TOT / 128, NHEAD, 8), 256, 0, stream>>>(
            qws, kws, vws, prt, mlw);
        attn_merge_kernel<4><<<dim3((2 * S_TOT * 64) / 256), 256, 0, stream>>>(prt, mlw, awb);
    } else {
        attn_mfma_kernel<32><<<dim3(S_TOT / 128, NHEAD, 4), 256, 0, stream>>>(
            qws, kws, vws, prt, mlw);
        attn_merge_kernel<2><<<dim3((2 * S_TOT * 64) / 256), 256, 0, stream>>>(prt, mlw, awb);
    }

    gemm_mfma_kernel<2><<<dim3(S_TOT / 128, CIN / 128, 2), 256, 0, stream>>>(
        wob, awb, out, b_out, HID, 0L, (long)S_TOT * HID);
}

// Round 12
// 179.797 us; speedup vs baseline: 1.0772x; 1.0772x over previous
//
#include <hip/hip_runtime.h>
#include <cmath>

#define S_TOT 4096
#define CIN   256
#define HID   512
#define NHEAD 8
#define DIMH  64

typedef __attribute__((ext_vector_type(8))) short bf16x8;
typedef __attribute__((ext_vector_type(4))) float f32x4;
typedef __attribute__((ext_vector_type(16))) float f32x16;
typedef __attribute__((address_space(1))) const void gv_t;
typedef __attribute__((address_space(3))) void lv_t;

__device__ __forceinline__ ushort f2bf(float f) {
    union { float f; unsigned u; } v; v.f = f;
    unsigned r = (v.u + 0x7FFFu + ((v.u >> 16) & 1u)) >> 16;
    return (ushort)r;
}

__device__ __forceinline__ float bf2f(ushort u) {
    union { unsigned u; float f; } v; v.u = ((unsigned)u) << 16; return v.f;
}

__device__ __forceinline__ float exp2_fast(float x) {
    float r; asm("v_exp_f32 %0, %1" : "=v"(r) : "v"(x)); return r;
}

__device__ __forceinline__ unsigned cvt_pk_bf16(float lo, float hi) {
    unsigned r; asm("v_cvt_pk_bf16_f32 %0, %1, %2" : "=v"(r) : "v"(lo), "v"(hi)); return r;
}

// 0.125 (1/sqrt(64)) * log2(e): folds softmax base-2 conversion into Q.
#define QSCALE 0.18033688011112042f

// ---------------------------------------------------------------------------
// Fused prologue: w_qkv cast (blocks 0..383), w_out cast (384..511),
// x transpose-cast (512..1023).
// ---------------------------------------------------------------------------
__global__ __launch_bounds__(256)
void prologue_kernel(const float* __restrict__ w_qkv, const float* __restrict__ w_out,
                     const float* __restrict__ x, ushort* __restrict__ wqb,
                     ushort* __restrict__ wob, ushort* __restrict__ xt) {
    __shared__ float tb[64][65];
    const int bid = blockIdx.x, t = threadIdx.x;
    if (bid < 512) {
        const float* src = (bid < 384) ? w_qkv : w_out;
        ushort* dst = (bid < 384) ? wqb : wob;
        const long i = ((long)(bid < 384 ? bid : bid - 384) * 256 + t) * 4;
        float4 v = *(const float4*)&src[i];
        ushort4 p;
        p.x = f2bf(v.x); p.y = f2bf(v.y); p.z = f2bf(v.z); p.w = f2bf(v.w);
        *(ushort4*)&dst[i] = p;
        return;
    }
    const int xb_ = bid - 512;              // [0,512): (s0/64) + 64*(c0/64 + 4*z)
    const int sx = xb_ & 63, rest = xb_ >> 6;
    const int cy = rest & 3, cz = rest >> 2;
    const int s0 = sx * 64, c0 = cy * 64;
    const long xb = (long)cz * CIN * S_TOT;
    #pragma unroll
    for (int i = 0; i < 16; ++i) {
        int idx = t + i * 256;
        int c = idx >> 6, s = idx & 63;
        tb[c][s] = x[xb + (long)(c0 + c) * S_TOT + s0 + s];
    }
    __syncthreads();
    const long ob = (long)cz * S_TOT * CIN;
    const int s = t >> 2, cq = (t & 3) * 16;
    #pragma unroll
    for (int j = 0; j < 4; ++j) {
        ushort4 pk;
        pk.x = f2bf(tb[cq + j * 4 + 0][s]);
        pk.y = f2bf(tb[cq + j * 4 + 1][s]);
        pk.z = f2bf(tb[cq + j * 4 + 2][s]);
        pk.w = f2bf(tb[cq + j * 4 + 3][s]);
        *(ushort4*)&xt[ob + (long)(s0 + s) * CIN + c0 + cq + j * 4] = pk;
    }
}

// ---------------------------------------------------------------------------
// bf16 MFMA GEMM (16x16x32).
// MODE 0: A=xt, B=w_qkv[0:1024] -> q (pre-scaled by QSCALE) / k, [bh][s][64]
// MODE 1: A=w_qkv[1024:1536], B=xt -> v [bh][d][s'] with key bits 2<->3
//         swapped within each 16-key group (matches attention's register-P).
// MODE 2: A=w_out, B=attn-bf16 -> out [b][o][s] fp32 + bias
// ---------------------------------------------------------------------------
template<int MODE>
__global__ __launch_bounds__(256)
void gemm_mfma_kernel(const ushort* __restrict__ Ag, const ushort* __restrict__ Bg,
                      void* __restrict__ outp, const float* __restrict__ bias,
                      int Kdim, long strideA, long strideB) {
    __shared__ __attribute__((aligned(16))) ushort Abuf[128 * 64];
    __shared__ __attribute__((aligned(16))) ushort Bbuf[128 * 64];
    const int t = threadIdx.x, lane = t & 63;
    const int l15 = lane & 15, g = lane >> 4;
    const int wid = t >> 6, wr = wid >> 1, wc = wid & 1;
    const int bz = blockIdx.z;
    const int am0 = blockIdx.y * 128, bn0 = blockIdx.x * 128;
    Ag += (long)bz * strideA;
    Bg += (long)bz * strideB;

    f32x4 acc[4][4];
    #pragma unroll
    for (int i = 0; i < 4; ++i)
        #pragma unroll
        for (int j = 0; j < 4; ++j)
            acc[i][j] = (f32x4){0.f, 0.f, 0.f, 0.f};

    for (int k0 = 0; k0 < Kdim; k0 += 64) {
        __syncthreads();
        #pragma unroll
        for (int i = 0; i < 4; ++i) {
            const int chunk = t + i * 256;
            const int row = chunk >> 3, sl = chunk & 7;
            const ushort* srcA = Ag + (long)(am0 + row) * Kdim + k0 + ((sl ^ (row & 7)) << 3);
            __builtin_amdgcn_global_load_lds((gv_t*)srcA,
                (lv_t*)((char*)Abuf + (i * 256 + (t & ~63)) * 16), 16, 0, 0);
            const ushort* srcB = Bg + (long)(bn0 + row) * Kdim + k0 + ((sl ^ (row & 7)) << 3);
            __builtin_amdgcn_global_load_lds((gv_t*)srcB,
                (lv_t*)((char*)Bbuf + (i * 256 + (t & ~63)) * 16), 16, 0, 0);
        }
        asm volatile("s_waitcnt vmcnt(0)" ::: "memory");
        __syncthreads();

        bf16x8 bfr[4][2];
        #pragma unroll
        for (int fn = 0; fn < 4; ++fn) {
            const int row = wc * 64 + fn * 16 + l15;
            #pragma unroll
            for (int hf = 0; hf < 2; ++hf)
                bfr[fn][hf] = *(const bf16x8*)((const char*)Bbuf + row * 128
                                + (((hf * 4 + g) ^ (row & 7)) << 4));
        }
        #pragma unroll
        for (int fm = 0; fm < 4; ++fm) {
            const int row = wr * 64 + fm * 16 + l15;
            const bf16x8 a0 = *(const bf16x8*)((const char*)Abuf + row * 128
                                + (((g) ^ (row & 7)) << 4));
            const bf16x8 a1 = *(const bf16x8*)((const char*)Abuf + row * 128
                                + (((4 + g) ^ (row & 7)) << 4));
            #pragma unroll
            for (int fn = 0; fn < 4; ++fn) {
                acc[fm][fn] = __builtin_amdgcn_mfma_f32_16x16x32_bf16(a0, bfr[fn][0], acc[fm][fn], 0, 0, 0);
                acc[fm][fn] = __builtin_amdgcn_mfma_f32_16x16x32_bf16(a1, bfr[fn][1], acc[fm][fn], 0, 0, 0);
            }
        }
    }

    #pragma unroll
    for (int fm = 0; fm < 4; ++fm)
        #pragma unroll
        for (int fn = 0; fn < 4; ++fn)
            #pragma unroll
            for (int r = 0; r < 4; ++r) {
                const int ar = am0 + wr * 64 + fm * 16 + g * 4 + r;
                const int bc = bn0 + wc * 64 + fn * 16 + l15;
                if (MODE == 0) {
                    const int which = bc >> 9, h = (bc >> 6) & 7, d = bc & 63;
                    const float scl = (which == 0) ? QSCALE : 1.0f;
                    ushort* O = (ushort*)outp;
                    O[(long)which * 4194304 + (((long)(bz * NHEAD + h)) * S_TOT + ar) * DIMH + d]
                        = f2bf(acc[fm][fn][r] * scl);
                } else if (MODE == 1) {
                    const int h = ar >> 6, d = ar & 63;
                    const int jm = bc & 15;
                    const int pjm = (jm & 3) | ((jm & 4) << 1) | ((jm & 8) >> 1);
                    const int pc = (bc & ~15) | pjm;
                    ushort* O = (ushort*)outp;
                    O[(((long)(bz * NHEAD + h)) * DIMH + d) * S_TOT + pc] = f2bf(acc[fm][fn][r]);
                } else {
                    float* O = (float*)outp;
                    O[((long)bz * CIN + ar) * S_TOT + bc] = acc[fm][fn][r] + bias[ar];
                }
            }
}

// ---------------------------------------------------------------------------
// Flash attention, 32x32x16, key-split x2 (round-9 proven regime: 1024
// blocks, FETCH ~70 MB, conflicts 0). Kept from round 10: per-q softmax sums
// via ones-B MFMAs into lacc (rows = per-q sums over all 64 keys) -> no
// per-lane adds, no epilogue shuffles. Overflow guard every 8 tiles.
// Grid z = sp*2 + b.
// ---------------------------------------------------------------------------
template<int NT>
__global__ __launch_bounds__(256, 4)
void attn_mfma_kernel(const ushort* __restrict__ qg, const ushort* __restrict__ kg,
                      const ushort* __restrict__ vg, ushort* __restrict__ pout,
                      float2* __restrict__ mlout) {
    __shared__ __attribute__((aligned(16))) ushort kbuf[2][64 * 64];
    __shared__ __attribute__((aligned(16))) ushort vbuf[2][64 * 64];

    const int t = threadIdx.x;
    const int lane = t & 63, wid = t >> 6;          // wid 0..3
    const int l31 = lane & 31, h = lane >> 5;
    const int head = blockIdx.y;
    const int sp = blockIdx.z >> 1, b = blockIdx.z & 1;
    const int bh = b * NHEAD + head;
    const int qrow0 = blockIdx.x * 128 + wid * 32;
    const long kbase = (long)sp * (NT * 64);

    const int sw_lo = (l31 ^ (l31 >> 3)) & 7;
    const int sw_hi = sw_lo ^ 4;

    // Q B-fragments: col q = l31, k(d) = ds*16 + 8h + j  (pre-scaled)
    const ushort* qp = qg + ((long)bh * S_TOT + qrow0 + l31) * DIMH + h * 8;
    bf16x8 qfr[4];
    #pragma unroll
    for (int ds = 0; ds < 4; ++ds) qfr[ds] = *(const bf16x8*)(qp + ds * 16);

    const short ONE = (short)0x3F80;
    const bf16x8 ones = {ONE, ONE, ONE, ONE, ONE, ONE, ONE, ONE};

    f32x16 oacc0 = {}, oacc1 = {}, lacc = {};
    f32x16 bias16 = {};                 // -(accumulated rescale) broadcast
    float nmr = 0.f;

    const long kg_base = (long)bh * S_TOT * DIMH;
    const long vg_base = (long)bh * DIMH * S_TOT;
    const int sl = lane & 7, sr = lane >> 3;

    auto STAGE = [&](int buf, long key0) {
        #pragma unroll
        for (int c = 0; c < 2; ++c) {
            const int row = wid * 16 + c * 8 + sr;          // row>>3 = wid*2+c
            const int sz = (sl ^ sr ^ (wid * 2 + c)) & 7;   // src chunk for slot sl
            char* kdst = (char*)(&kbuf[buf][0]) + wid * 2048 + c * 1024;
            char* vdst = (char*)(&vbuf[buf][0]) + wid * 2048 + c * 1024;
            const char* srcK = (const char*)(kg + kg_base + (key0 + row) * DIMH) + (sz << 4);
            __builtin_amdgcn_global_load_lds((gv_t*)srcK, (lv_t*)kdst, 16, 0, 0);
            const char* srcV = (const char*)(vg + vg_base + (long)row * S_TOT + key0) + (sz << 4);
            __builtin_amdgcn_global_load_lds((gv_t*)srcV, (lv_t*)vdst, 16, 0, 0);
        }
    };

    STAGE(0, kbase);
    asm volatile("s_waitcnt vmcnt(0)" ::: "memory");
    __syncthreads();

    for (int kt0 = 0; kt0 < NT; ++kt0) {
        const int cur = kt0 & 1;
        if (kt0 + 1 < NT) STAGE(cur ^ 1, kbase + (long)(kt0 + 1) * 64);

        const char* kb_ = (const char*)(&kbuf[cur][0]);
        const char* vb_ = (const char*)(&vbuf[cur][0]);

        // --- S^T = K Q^T + bias: lane q=l31; key = 32kg + (r&3)+8(r>>2)+4h
        f32x16 s0, s1;
        __builtin_amdgcn_s_setprio(1);
        {
            const bf16x8 kf0 = *(const bf16x8*)(kb_ + l31 * 128 + ((h ^ sw_lo) << 4));
            const bf16x8 kf1 = *(const bf16x8*)(kb_ + 4096 + l31 * 128 + ((h ^ sw_hi) << 4));
            s0 = __builtin_amdgcn_mfma_f32_32x32x16_bf16(kf0, qfr[0], bias16, 0, 0, 0);
            s1 = __builtin_amdgcn_mfma_f32_32x32x16_bf16(kf1, qfr[0], bias16, 0, 0, 0);
        }
        #pragma unroll
        for (int ds = 1; ds < 4; ++ds) {
            const bf16x8 kf0 = *(const bf16x8*)(kb_ + l31 * 128 + (((2 * ds + h) ^ sw_lo) << 4));
            const bf16x8 kf1 = *(const bf16x8*)(kb_ + 4096 + l31 * 128 + (((2 * ds + h) ^ sw_hi) << 4));
            s0 = __builtin_amdgcn_mfma_f32_32x32x16_bf16(kf0, qfr[ds], s0, 0, 0, 0);
            s1 = __builtin_amdgcn_mfma_f32_32x32x16_bf16(kf1, qfr[ds], s1, 0, 0, 0);
        }
        __builtin_amdgcn_s_setprio(0);

        // --- exp + pack P directly (V key order pre-swapped in global) ---
        bf16x8 pf0, pf1, pf2, pf3;
        {
            float e[16];
            #pragma unroll
            for (int r = 0; r < 16; ++r) e[r] = exp2_fast(s0[r]);
            union { unsigned u[4]; bf16x8 v; } A_, B_;
            #pragma unroll
            for (int w = 0; w < 4; ++w) A_.u[w] = cvt_pk_bf16(e[2 * w], e[2 * w + 1]);
            #pragma unroll
            for (int w = 0; w < 4; ++w) B_.u[w] = cvt_pk_bf16(e[8 + 2 * w], e[9 + 2 * w]);
            pf0 = A_.v; pf1 = B_.v;
        }
        {
            float e[16];
            #pragma unroll
            for (int r = 0; r < 16; ++r) e[r] = exp2_fast(s1[r]);
            union { unsigned u[4]; bf16x8 v; } A_, B_;
            #pragma unroll
            for (int w = 0; w < 4; ++w) A_.u[w] = cvt_pk_bf16(e[2 * w], e[2 * w + 1]);
            #pragma unroll
            for (int w = 0; w < 4; ++w) B_.u[w] = cvt_pk_bf16(e[8 + 2 * w], e[9 + 2 * w]);
            pf2 = A_.v; pf3 = B_.v;
        }

        // --- O += P V; lsum += P * ones ---
        __builtin_amdgcn_s_setprio(1);
        {
            const bf16x8 vf00 = *(const bf16x8*)(vb_ + l31 * 128 + ((h ^ sw_lo) << 4));
            const bf16x8 vf01 = *(const bf16x8*)(vb_ + 4096 + l31 * 128 + ((h ^ sw_hi) << 4));
            oacc0 = __builtin_amdgcn_mfma_f32_32x32x16_bf16(pf0, vf00, oacc0, 0, 0, 0);
            oacc1 = __builtin_amdgcn_mfma_f32_32x32x16_bf16(pf0, vf01, oacc1, 0, 0, 0);
            lacc  = __builtin_amdgcn_mfma_f32_32x32x16_bf16(pf0, ones, lacc, 0, 0, 0);
            const bf16x8 vf10 = *(const bf16x8*)(vb_ + l31 * 128 + (((2 + h) ^ sw_lo) << 4));
            const bf16x8 vf11 = *(const bf16x8*)(vb_ + 4096 + l31 * 128 + (((2 + h) ^ sw_hi) << 4));
            oacc0 = __builtin_amdgcn_mfma_f32_32x32x16_bf16(pf1, vf10, oacc0, 0, 0, 0);
            oacc1 = __builtin_amdgcn_mfma_f32_32x32x16_bf16(pf1, vf11, oacc1, 0, 0, 0);
            lacc  = __builtin_amdgcn_mfma_f32_32x32x16_bf16(pf1, ones, lacc, 0, 0, 0);
            const bf16x8 vf20 = *(const bf16x8*)(vb_ + l31 * 128 + (((4 + h) ^ sw_lo) << 4));
            const bf16x8 vf21 = *(const bf16x8*)(vb_ + 4096 + l31 * 128 + (((4 + h) ^ sw_hi) << 4));
            oacc0 = __builtin_amdgcn_mfma_f32_32x32x16_bf16(pf2, vf20, oacc0, 0, 0, 0);
            oacc1 = __builtin_amdgcn_mfma_f32_32x32x16_bf16(pf2, vf21, oacc1, 0, 0, 0);
            lacc  = __builtin_amdgcn_mfma_f32_32x32x16_bf16(pf2, ones, lacc, 0, 0, 0);
            const bf16x8 vf30 = *(const bf16x8*)(vb_ + l31 * 128 + (((6 + h) ^ sw_lo) << 4));
            const bf16x8 vf31 = *(const bf16x8*)(vb_ + 4096 + l31 * 128 + (((6 + h) ^ sw_hi) << 4));
            oacc0 = __builtin_amdgcn_mfma_f32_32x32x16_bf16(pf3, vf30, oacc0, 0, 0, 0);
            oacc1 = __builtin_amdgcn_mfma_f32_32x32x16_bf16(pf3, vf31, oacc1, 0, 0, 0);
            lacc  = __builtin_amdgcn_mfma_f32_32x32x16_bf16(pf3, ones, lacc, 0, 0, 0);
        }
        __builtin_amdgcn_s_setprio(0);

        // --- rare overflow guard, checked every 8 tiles ---
        if ((kt0 & 7) == 7) {
            float mx = lacc[0];
            #pragma unroll
            for (int r = 1; r < 16; ++r) mx = fmaxf(mx, lacc[r]);
            if (__any(mx > 1.8446744e19f)) {          // 2^64
                const float sc = 3.5527136788e-15f;   // 2^-48
                #pragma unroll
                for (int r = 0; r < 16; ++r) {
                    oacc0[r] *= sc; oacc1[r] *= sc; lacc[r] *= sc;
                }
                nmr -= 48.0f;
                #pragma unroll
                for (int r = 0; r < 16; ++r) bias16[r] = nmr;
            }
        }

        asm volatile("s_waitcnt vmcnt(0)" ::: "memory");
        __syncthreads();
    }

    // epilogue: unnormalized partial O (bf16) + per-q (m, l) fp32 (no shuffles)
    const long pbase = (((long)sp * 2 + b) * S_TOT) * HID;
    #pragma unroll
    for (int r = 0; r < 16; ++r) {
        const int q = (r & 3) + 8 * (r >> 2) + 4 * h;
        const long off = pbase + (long)(qrow0 + q) * HID + head * 64 + l31;
        pout[off]      = f2bf(oacc0[r]);
        pout[off + 32] = f2bf(oacc1[r]);
    }
    if (l31 == 0) {
        float2* mlp = mlout + ((long)sp * 2 * NHEAD * S_TOT) + (long)bh * S_TOT + qrow0;
        #pragma unroll
        for (int r = 0; r < 16; ++r) {
            const int q = (r & 3) + 8 * (r >> 2) + 4 * h;
            mlp[q] = make_float2(-nmr, lacc[r]);
        }
    }
}

// ---------------------------------------------------------------------------
// Merge SP key-split partials: out = sum_i w_i*O_i / sum_i w_i*l_i,
// w_i = 2^(m_i - max m). One thread = 8 hd of one (b,q).
// ---------------------------------------------------------------------------
template<int SP>
__global__ __launch_bounds__(256)
void attn_merge_kernel(const ushort* __restrict__ part, const float2* __restrict__ ml,
                       ushort* __restrict__ aout) {
    const long i = (long)blockIdx.x * 256 + threadIdx.x;   // [0, 2*4096*64)
    const int hd8 = (int)(i & 63);
    const long bq = i >> 6;
    const int q = (int)(bq & (S_TOT - 1)), b = (int)(bq >> 12);
    const int h = hd8 >> 3;
    const long mlsp = (long)2 * NHEAD * S_TOT;
    const long mlidx = (long)(b * NHEAD + h) * S_TOT + q;
    float2 mls[SP];
    float m = -3e38f;
    #pragma unroll
    for (int sp = 0; sp < SP; ++sp) {
        mls[sp] = ml[sp * mlsp + mlidx];
        m = fmaxf(m, mls[sp].x);
    }
    float w[SP];
    float wsum = 0.f;
    #pragma unroll
    for (int sp = 0; sp < SP; ++sp) {
        w[sp] = exp2_fast(mls[sp].x - m);
        wsum += w[sp] * mls[sp].y;
    }
    const float inv = 1.0f / wsum;
    const long psp = (long)2 * S_TOT * HID;
    const long off = ((long)b * S_TOT + q) * HID + hd8 * 8;
    float acc[8] = {};
    #pragma unroll
    for (int sp = 0; sp < SP; ++sp) {
        const bf16x8 p = *(const bf16x8*)&part[sp * psp + off];
        #pragma unroll
        for (int j = 0; j < 8; ++j) acc[j] += w[sp] * bf2f((ushort)p[j]);
    }
    union { ushort u[8]; bf16x8 v; } o;
    #pragma unroll
    for (int j = 0; j < 8; ++j) o.u[j] = f2bf(acc[j] * inv);
    *(bf16x8*)&aout[off] = o.v;
}

// ---------------------------------------------------------------------------
extern "C" void kernel_launch(void* const* d_in, const int* in_sizes, int n_in,
                              void* d_out, int out_size, void* d_ws, size_t ws_size,
                              hipStream_t stream) {
    const float* x     = (const float*)d_in[0];
    const float* w_qkv = (const float*)d_in[1];
    const float* w_out = (const float*)d_in[2];
    const float* b_out = (const float*)d_in[3];
    float* out = (float*)d_out;

    const long PERQKV = (long)2 * NHEAD * S_TOT * DIMH;   // 4,194,304
    ushort* qws = (ushort*)d_ws;
    ushort* kws = qws + PERQKV;
    ushort* vws = kws + PERQKV;
    ushort* xt  = vws + PERQKV;                           // 2*4096*256
    ushort* wqb = xt + (long)2 * S_TOT * CIN;             // 1536*256
    ushort* wob = wqb + (long)3 * HID * CIN;              // 256*512
    ushort* awb = wob + (long)CIN * HID;                  // 2*4096*512
    ushort* prt = awb + (long)2 * S_TOT * HID;            // 2 splits * 2*4096*512
    float2* mlw = (float2*)(prt + (long)4 * S_TOT * HID); // 2*16*4096 float2

    prologue_kernel<<<dim3(1024), 256, 0, stream>>>(w_qkv, w_out, x, wqb, wob, xt);

    gemm_mfma_kernel<0><<<dim3(1024 / 128, S_TOT / 128, 2), 256, 0, stream>>>(
        xt, wqb, qws, nullptr, CIN, (long)S_TOT * CIN, 0L);
    gemm_mfma_kernel<1><<<dim3(S_TOT / 128, 512 / 128, 2), 256, 0, stream>>>(
        wqb + (long)1024 * CIN, xt, vws, nullptr, CIN, 0L, (long)S_TOT * CIN);

    attn_mfma_kernel<32><<<dim3(S_TOT / 128, NHEAD, 4), 256, 0, stream>>>(
        qws, kws, vws, prt, mlw);
    attn_merge_kernel<2><<<dim3((2 * S_TOT * 64) / 256), 256, 0, stream>>>(prt, mlw, awb);

    gemm_mfma_kernel<2><<<dim3(S_TOT / 128, CIN / 128, 2), 256, 0, stream>>>(
        wob, awb, out, b_out, HID, 0L, (long)S_TOT * HID);
}

// Round 13
// 122.321 us; speedup vs baseline: 1.5834x; 1.4699x over previous
//
#include <hip/hip_runtime.h>
#include <cmath>

#define S_TOT 4096
#define CIN   256
#define HID   512
#define NHEAD 8
#define DIMH  64

typedef __attribute__((ext_vector_type(8))) short bf16x8;
typedef __attribute__((ext_vector_type(4))) float f32x4;
typedef __attribute__((ext_vector_type(16))) float f32x16;
typedef __attribute__((address_space(1))) const void gv_t;
typedef __attribute__((address_space(3))) void lv_t;

__device__ __forceinline__ ushort f2bf(float f) {
    union { float f; unsigned u; } v; v.f = f;
    unsigned r = (v.u + 0x7FFFu + ((v.u >> 16) & 1u)) >> 16;
    return (ushort)r;
}

__device__ __forceinline__ float bf2f(ushort u) {
    union { unsigned u; float f; } v; v.u = ((unsigned)u) << 16; return v.f;
}

__device__ __forceinline__ float exp2_fast(float x) {
    float r; asm("v_exp_f32 %0, %1" : "=v"(r) : "v"(x)); return r;
}

__device__ __forceinline__ unsigned cvt_pk_bf16(float lo, float hi) {
    unsigned r; asm("v_cvt_pk_bf16_f32 %0, %1, %2" : "=v"(r) : "v"(lo), "v"(hi)); return r;
}

// 0.125 (1/sqrt(64)) * log2(e): folds softmax base-2 conversion into Q.
#define QSCALE 0.18033688011112042f

// ---------------------------------------------------------------------------
// Fused prologue: w_qkv cast (blocks 0..383), w_out cast (384..511),
// x transpose-cast (512..1023).
// ---------------------------------------------------------------------------
__global__ __launch_bounds__(256)
void prologue_kernel(const float* __restrict__ w_qkv, const float* __restrict__ w_out,
                     const float* __restrict__ x, ushort* __restrict__ wqb,
                     ushort* __restrict__ wob, ushort* __restrict__ xt) {
    __shared__ float tb[64][65];
    const int bid = blockIdx.x, t = threadIdx.x;
    if (bid < 512) {
        const float* src = (bid < 384) ? w_qkv : w_out;
        ushort* dst = (bid < 384) ? wqb : wob;
        const long i = ((long)(bid < 384 ? bid : bid - 384) * 256 + t) * 4;
        float4 v = *(const float4*)&src[i];
        ushort4 p;
        p.x = f2bf(v.x); p.y = f2bf(v.y); p.z = f2bf(v.z); p.w = f2bf(v.w);
        *(ushort4*)&dst[i] = p;
        return;
    }
    const int xb_ = bid - 512;              // [0,512): (s0/64) + 64*(c0/64 + 4*z)
    const int sx = xb_ & 63, rest = xb_ >> 6;
    const int cy = rest & 3, cz = rest >> 2;
    const int s0 = sx * 64, c0 = cy * 64;
    const long xb = (long)cz * CIN * S_TOT;
    #pragma unroll
    for (int i = 0; i < 16; ++i) {
        int idx = t + i * 256;
        int c = idx >> 6, s = idx & 63;
        tb[c][s] = x[xb + (long)(c0 + c) * S_TOT + s0 + s];
    }
    __syncthreads();
    const long ob = (long)cz * S_TOT * CIN;
    const int s = t >> 2, cq = (t & 3) * 16;
    #pragma unroll
    for (int j = 0; j < 4; ++j) {
        ushort4 pk;
        pk.x = f2bf(tb[cq + j * 4 + 0][s]);
        pk.y = f2bf(tb[cq + j * 4 + 1][s]);
        pk.z = f2bf(tb[cq + j * 4 + 2][s]);
        pk.w = f2bf(tb[cq + j * 4 + 3][s]);
        *(ushort4*)&xt[ob + (long)(s0 + s) * CIN + c0 + cq + j * 4] = pk;
    }
}

// ---------------------------------------------------------------------------
// bf16 MFMA GEMM (16x16x32).
// MODE 0: A=xt, B=w_qkv[0:1024] -> q (pre-scaled by QSCALE) / k, [bh][s][64]
// MODE 1: A=w_qkv[1024:1536], B=xt -> v [bh][d][s'] with key bits 2<->3
//         swapped within each 16-key group (matches attention's register-P).
// MODE 2: A=w_out, B=attn-bf16 -> out [b][o][s] fp32 + bias
// ---------------------------------------------------------------------------
template<int MODE>
__global__ __launch_bounds__(256)
void gemm_mfma_kernel(const ushort* __restrict__ Ag, const ushort* __restrict__ Bg,
                      void* __restrict__ outp, const float* __restrict__ bias,
                      int Kdim, long strideA, long strideB) {
    __shared__ __attribute__((aligned(16))) ushort Abuf[128 * 64];
    __shared__ __attribute__((aligned(16))) ushort Bbuf[128 * 64];
    const int t = threadIdx.x, lane = t & 63;
    const int l15 = lane & 15, g = lane >> 4;
    const int wid = t >> 6, wr = wid >> 1, wc = wid & 1;
    const int bz = blockIdx.z;
    const int am0 = blockIdx.y * 128, bn0 = blockIdx.x * 128;
    Ag += (long)bz * strideA;
    Bg += (long)bz * strideB;

    f32x4 acc[4][4];
    #pragma unroll
    for (int i = 0; i < 4; ++i)
        #pragma unroll
        for (int j = 0; j < 4; ++j)
            acc[i][j] = (f32x4){0.f, 0.f, 0.f, 0.f};

    for (int k0 = 0; k0 < Kdim; k0 += 64) {
        __syncthreads();
        #pragma unroll
        for (int i = 0; i < 4; ++i) {
            const int chunk = t + i * 256;
            const int row = chunk >> 3, sl = chunk & 7;
            const ushort* srcA = Ag + (long)(am0 + row) * Kdim + k0 + ((sl ^ (row & 7)) << 3);
            __builtin_amdgcn_global_load_lds((gv_t*)srcA,
                (lv_t*)((char*)Abuf + (i * 256 + (t & ~63)) * 16), 16, 0, 0);
            const ushort* srcB = Bg + (long)(bn0 + row) * Kdim + k0 + ((sl ^ (row & 7)) << 3);
            __builtin_amdgcn_global_load_lds((gv_t*)srcB,
                (lv_t*)((char*)Bbuf + (i * 256 + (t & ~63)) * 16), 16, 0, 0);
        }
        asm volatile("s_waitcnt vmcnt(0)" ::: "memory");
        __syncthreads();

        bf16x8 bfr[4][2];
        #pragma unroll
        for (int fn = 0; fn < 4; ++fn) {
            const int row = wc * 64 + fn * 16 + l15;
            #pragma unroll
            for (int hf = 0; hf < 2; ++hf)
                bfr[fn][hf] = *(const bf16x8*)((const char*)Bbuf + row * 128
                                + (((hf * 4 + g) ^ (row & 7)) << 4));
        }
        #pragma unroll
        for (int fm = 0; fm < 4; ++fm) {
            const int row = wr * 64 + fm * 16 + l15;
            const bf16x8 a0 = *(const bf16x8*)((const char*)Abuf + row * 128
                                + (((g) ^ (row & 7)) << 4));
            const bf16x8 a1 = *(const bf16x8*)((const char*)Abuf + row * 128
                                + (((4 + g) ^ (row & 7)) << 4));
            #pragma unroll
            for (int fn = 0; fn < 4; ++fn) {
                acc[fm][fn] = __builtin_amdgcn_mfma_f32_16x16x32_bf16(a0, bfr[fn][0], acc[fm][fn], 0, 0, 0);
                acc[fm][fn] = __builtin_amdgcn_mfma_f32_16x16x32_bf16(a1, bfr[fn][1], acc[fm][fn], 0, 0, 0);
            }
        }
    }

    #pragma unroll
    for (int fm = 0; fm < 4; ++fm)
        #pragma unroll
        for (int fn = 0; fn < 4; ++fn)
            #pragma unroll
            for (int r = 0; r < 4; ++r) {
                const int ar = am0 + wr * 64 + fm * 16 + g * 4 + r;
                const int bc = bn0 + wc * 64 + fn * 16 + l15;
                if (MODE == 0) {
                    const int which = bc >> 9, h = (bc >> 6) & 7, d = bc & 63;
                    const float scl = (which == 0) ? QSCALE : 1.0f;
                    ushort* O = (ushort*)outp;
                    O[(long)which * 4194304 + (((long)(bz * NHEAD + h)) * S_TOT + ar) * DIMH + d]
                        = f2bf(acc[fm][fn][r] * scl);
                } else if (MODE == 1) {
                    const int h = ar >> 6, d = ar & 63;
                    const int jm = bc & 15;
                    const int pjm = (jm & 3) | ((jm & 4) << 1) | ((jm & 8) >> 1);
                    const int pc = (bc & ~15) | pjm;
                    ushort* O = (ushort*)outp;
                    O[(((long)(bz * NHEAD + h)) * DIMH + d) * S_TOT + pc] = f2bf(acc[fm][fn][r]);
                } else {
                    float* O = (float*)outp;
                    O[((long)bz * CIN + ar) * S_TOT + bc] = acc[fm][fn][r] + bias[ar];
                }
            }
}

// ---------------------------------------------------------------------------
// Flash attention, 32x32x16, key-split x2 — EXACT round-9 version (measured
// 83.9 us, FETCH 70.7 MB, WRITE 19.5 MB, conflicts 0). Per-lane lrun adds,
// per-tile overflow guard, h==0 coalesced ml write, z = b*2 + sp mapping.
// ---------------------------------------------------------------------------
__global__ __launch_bounds__(256, 4)
void attn_mfma_kernel(const ushort* __restrict__ qg, const ushort* __restrict__ kg,
                      const ushort* __restrict__ vg, ushort* __restrict__ pout,
                      float2* __restrict__ mlout) {
    __shared__ __attribute__((aligned(16))) ushort kbuf[2][64 * 64];
    __shared__ __attribute__((aligned(16))) ushort vbuf[2][64 * 64];

    const int t = threadIdx.x;
    const int lane = t & 63, wid = t >> 6;          // wid 0..3
    const int l31 = lane & 31, h = lane >> 5;
    const int head = blockIdx.y;
    const int b = blockIdx.z >> 1, sp = blockIdx.z & 1;
    const int bh = b * NHEAD + head;
    const int qrow0 = blockIdx.x * 128 + wid * 32;
    const long kbase = (long)sp * (S_TOT / 2);

    const int sw_lo = (l31 ^ (l31 >> 3)) & 7;
    const int sw_hi = sw_lo ^ 4;

    // Q B-fragments: col q = l31, k(d) = ds*16 + 8h + j  (pre-scaled)
    const ushort* qp = qg + ((long)bh * S_TOT + qrow0 + l31) * DIMH + h * 8;
    bf16x8 qfr[4];
    #pragma unroll
    for (int ds = 0; ds < 4; ++ds) qfr[ds] = *(const bf16x8*)(qp + ds * 16);

    f32x16 oacc0 = {}, oacc1 = {};
    f32x16 bias16 = {};                 // -(accumulated rescale) broadcast
    float nmr = 0.f, lrun = 0.f;        // per-lane, q = l31 domain

    const long kg_base = (long)bh * S_TOT * DIMH;
    const long vg_base = (long)bh * DIMH * S_TOT;
    const int sl = lane & 7, sr = lane >> 3;

    auto STAGE = [&](int buf, long key0) {
        #pragma unroll
        for (int c = 0; c < 2; ++c) {
            const int row = wid * 16 + c * 8 + sr;          // row>>3 = wid*2+c
            const int sz = (sl ^ sr ^ (wid * 2 + c)) & 7;   // src chunk for slot sl
            char* kdst = (char*)(&kbuf[buf][0]) + wid * 2048 + c * 1024;
            char* vdst = (char*)(&vbuf[buf][0]) + wid * 2048 + c * 1024;
            const char* srcK = (const char*)(kg + kg_base + (key0 + row) * DIMH) + (sz << 4);
            __builtin_amdgcn_global_load_lds((gv_t*)srcK, (lv_t*)kdst, 16, 0, 0);
            const char* srcV = (const char*)(vg + vg_base + (long)row * S_TOT + key0) + (sz << 4);
            __builtin_amdgcn_global_load_lds((gv_t*)srcV, (lv_t*)vdst, 16, 0, 0);
        }
    };

    STAGE(0, kbase);
    asm volatile("s_waitcnt vmcnt(0)" ::: "memory");
    __syncthreads();

    const int NT = (S_TOT / 2) / 64;   // 32 tiles per split
    for (int kt0 = 0; kt0 < NT; ++kt0) {
        const int cur = kt0 & 1;
        if (kt0 + 1 < NT) STAGE(cur ^ 1, kbase + (long)(kt0 + 1) * 64);

        const char* kb_ = (const char*)(&kbuf[cur][0]);
        const char* vb_ = (const char*)(&vbuf[cur][0]);

        // --- S^T = K Q^T + bias: lane q=l31; key = 32kg + (r&3)+8(r>>2)+4h
        f32x16 s0, s1;
        __builtin_amdgcn_s_setprio(1);
        {
            const bf16x8 kf0 = *(const bf16x8*)(kb_ + l31 * 128 + ((h ^ sw_lo) << 4));
            const bf16x8 kf1 = *(const bf16x8*)(kb_ + 4096 + l31 * 128 + ((h ^ sw_hi) << 4));
            s0 = __builtin_amdgcn_mfma_f32_32x32x16_bf16(kf0, qfr[0], bias16, 0, 0, 0);
            s1 = __builtin_amdgcn_mfma_f32_32x32x16_bf16(kf1, qfr[0], bias16, 0, 0, 0);
        }
        #pragma unroll
        for (int ds = 1; ds < 4; ++ds) {
            const bf16x8 kf0 = *(const bf16x8*)(kb_ + l31 * 128 + (((2 * ds + h) ^ sw_lo) << 4));
            const bf16x8 kf1 = *(const bf16x8*)(kb_ + 4096 + l31 * 128 + (((2 * ds + h) ^ sw_hi) << 4));
            s0 = __builtin_amdgcn_mfma_f32_32x32x16_bf16(kf0, qfr[ds], s0, 0, 0, 0);
            s1 = __builtin_amdgcn_mfma_f32_32x32x16_bf16(kf1, qfr[ds], s1, 0, 0, 0);
        }
        __builtin_amdgcn_s_setprio(0);

        // --- exp + pack P directly (V key order pre-swapped in global) ---
        bf16x8 pf0, pf1, pf2, pf3;
        {
            float e[16];
            #pragma unroll
            for (int r = 0; r < 16; ++r) e[r] = exp2_fast(s0[r]);
            #pragma unroll
            for (int r = 0; r < 16; ++r) lrun += e[r];
            union { unsigned u[4]; bf16x8 v; } A_, B_;
            #pragma unroll
            for (int w = 0; w < 4; ++w) A_.u[w] = cvt_pk_bf16(e[2 * w], e[2 * w + 1]);
            #pragma unroll
            for (int w = 0; w < 4; ++w) B_.u[w] = cvt_pk_bf16(e[8 + 2 * w], e[9 + 2 * w]);
            pf0 = A_.v; pf1 = B_.v;
        }
        {
            float e[16];
            #pragma unroll
            for (int r = 0; r < 16; ++r) e[r] = exp2_fast(s1[r]);
            #pragma unroll
            for (int r = 0; r < 16; ++r) lrun += e[r];
            union { unsigned u[4]; bf16x8 v; } A_, B_;
            #pragma unroll
            for (int w = 0; w < 4; ++w) A_.u[w] = cvt_pk_bf16(e[2 * w], e[2 * w + 1]);
            #pragma unroll
            for (int w = 0; w < 4; ++w) B_.u[w] = cvt_pk_bf16(e[8 + 2 * w], e[9 + 2 * w]);
            pf2 = A_.v; pf3 = B_.v;
        }

        // --- O += P V: A = P (regs), B = V (LDS [d][key']) ---
        __builtin_amdgcn_s_setprio(1);
        {
            const bf16x8 vf00 = *(const bf16x8*)(vb_ + l31 * 128 + ((h ^ sw_lo) << 4));
            const bf16x8 vf01 = *(const bf16x8*)(vb_ + 4096 + l31 * 128 + ((h ^ sw_hi) << 4));
            oacc0 = __builtin_amdgcn_mfma_f32_32x32x16_bf16(pf0, vf00, oacc0, 0, 0, 0);
            oacc1 = __builtin_amdgcn_mfma_f32_32x32x16_bf16(pf0, vf01, oacc1, 0, 0, 0);
            const bf16x8 vf10 = *(const bf16x8*)(vb_ + l31 * 128 + (((2 + h) ^ sw_lo) << 4));
            const bf16x8 vf11 = *(const bf16x8*)(vb_ + 4096 + l31 * 128 + (((2 + h) ^ sw_hi) << 4));
            oacc0 = __builtin_amdgcn_mfma_f32_32x32x16_bf16(pf1, vf10, oacc0, 0, 0, 0);
            oacc1 = __builtin_amdgcn_mfma_f32_32x32x16_bf16(pf1, vf11, oacc1, 0, 0, 0);
            const bf16x8 vf20 = *(const bf16x8*)(vb_ + l31 * 128 + (((4 + h) ^ sw_lo) << 4));
            const bf16x8 vf21 = *(const bf16x8*)(vb_ + 4096 + l31 * 128 + (((4 + h) ^ sw_hi) << 4));
            oacc0 = __builtin_amdgcn_mfma_f32_32x32x16_bf16(pf2, vf20, oacc0, 0, 0, 0);
            oacc1 = __builtin_amdgcn_mfma_f32_32x32x16_bf16(pf2, vf21, oacc1, 0, 0, 0);
            const bf16x8 vf30 = *(const bf16x8*)(vb_ + l31 * 128 + (((6 + h) ^ sw_lo) << 4));
            const bf16x8 vf31 = *(const bf16x8*)(vb_ + 4096 + l31 * 128 + (((6 + h) ^ sw_hi) << 4));
            oacc0 = __builtin_amdgcn_mfma_f32_32x32x16_bf16(pf3, vf30, oacc0, 0, 0, 0);
            oacc1 = __builtin_amdgcn_mfma_f32_32x32x16_bf16(pf3, vf31, oacc1, 0, 0, 0);
        }
        __builtin_amdgcn_s_setprio(0);

        // --- rare uniform overflow guard (keeps fp32/bf16 in range for any data)
        if (__any(lrun > 1.6777216e7f)) {       // 2^24
            const float sc = 5.9604644775390625e-8f;   // 2^-24
            lrun *= sc;
            #pragma unroll
            for (int r = 0; r < 16; ++r) { oacc0[r] *= sc; oacc1[r] *= sc; }
            nmr -= 24.0f;
            #pragma unroll
            for (int r = 0; r < 16; ++r) bias16[r] = nmr;
        }

        asm volatile("s_waitcnt vmcnt(0)" ::: "memory");
        __syncthreads();
    }

    // epilogue: write unnormalized partial O (bf16) + per-q (m, l) fp32
    lrun += __shfl_xor(lrun, 32, 64);                 // full sum per q=l31
    const long pbase = (((long)sp * 2 + b) * S_TOT) * HID;
    #pragma unroll
    for (int r = 0; r < 16; ++r) {
        const int q = (r & 3) + 8 * (r >> 2) + 4 * h;
        const long off = pbase + (long)(qrow0 + q) * HID + head * 64 + l31;
        pout[off]      = f2bf(oacc0[r]);
        pout[off + 32] = f2bf(oacc1[r]);
    }
    if (h == 0)
        mlout[((long)sp * 2 * NHEAD * S_TOT) + (long)bh * S_TOT + qrow0 + l31]
            = make_float2(-nmr, lrun);
}

// ---------------------------------------------------------------------------
// Merge the two key-split halves: out = (w0*O0 + w1*O1) / (w0*l0 + w1*l1),
// w_i = 2^(m_i - max(m0,m1)). One thread = 8 hd of one (b,q).
// ---------------------------------------------------------------------------
__global__ __launch_bounds__(256)
void attn_merge_kernel(const ushort* __restrict__ part, const float2* __restrict__ ml,
                       ushort* __restrict__ aout) {
    const long i = (long)blockIdx.x * 256 + threadIdx.x;   // [0, 2*4096*64)
    const int hd8 = (int)(i & 63);
    const long bq = i >> 6;
    const int q = (int)(bq & (S_TOT - 1)), b = (int)(bq >> 12);
    const int h = hd8 >> 3;
    const long mlst = (long)2 * NHEAD * S_TOT;
    const float2 ml0 = ml[(long)(b * NHEAD + h) * S_TOT + q];
    const float2 ml1 = ml[mlst + (long)(b * NHEAD + h) * S_TOT + q];
    const float m = fmaxf(ml0.x, ml1.x);
    const float w0 = exp2_fast(ml0.x - m), w1 = exp2_fast(ml1.x - m);
    const float inv = 1.0f / (w0 * ml0.y + w1 * ml1.y);
    const long phalf = (long)2 * S_TOT * HID;
    const long off = ((long)b * S_TOT + q) * HID + hd8 * 8;
    const bf16x8 p0 = *(const bf16x8*)&part[off];
    const bf16x8 p1 = *(const bf16x8*)&part[phalf + off];
    union { ushort u[8]; bf16x8 v; } o;
    #pragma unroll
    for (int j = 0; j < 8; ++j)
        o.u[j] = f2bf((w0 * bf2f((ushort)p0[j]) + w1 * bf2f((ushort)p1[j])) * inv);
    *(bf16x8*)&aout[off] = o.v;
}

// ---------------------------------------------------------------------------
extern "C" void kernel_launch(void* const* d_in, const int* in_sizes, int n_in,
                              void* d_out, int out_size, void* d_ws, size_t ws_size,
                              hipStream_t stream) {
    const float* x     = (const float*)d_in[0];
    const float* w_qkv = (const float*)d_in[1];
    const float* w_out = (const float*)d_in[2];
    const float* b_out = (const float*)d_in[3];
    float* out = (float*)d_out;

    const long PERQKV = (long)2 * NHEAD * S_TOT * DIMH;   // 4,194,304
    ushort* qws = (ushort*)d_ws;
    ushort* kws = qws + PERQKV;
    ushort* vws = kws + PERQKV;
    ushort* xt  = vws + PERQKV;                           // 2*4096*256
    ushort* wqb = xt + (long)2 * S_TOT * CIN;             // 1536*256
    ushort* wob = wqb + (long)3 * HID * CIN;              // 256*512
    ushort* awb = wob + (long)CIN * HID;                  // 2*4096*512
    ushort* prt = awb + (long)2 * S_TOT * HID;            // 2 splits * 2*4096*512
    float2* mlw = (float2*)(prt + (long)4 * S_TOT * HID); // 2*16*4096 float2

    prologue_kernel<<<dim3(1024), 256, 0, stream>>>(w_qkv, w_out, x, wqb, wob, xt);

    gemm_mfma_kernel<0><<<dim3(1024 / 128, S_TOT / 128, 2), 256, 0, stream>>>(
        xt, wqb, qws, nullptr, CIN, (long)S_TOT * CIN, 0L);
    gemm_mfma_kernel<1><<<dim3(S_TOT / 128, 512 / 128, 2), 256, 0, stream>>>(
        wqb + (long)1024 * CIN, xt, vws, nullptr, CIN, 0L, (long)S_TOT * CIN);

    attn_mfma_kernel<<<dim3(S_TOT / 128, NHEAD, 4), 256, 0, stream>>>(
        qws, kws, vws, prt, mlw);
    attn_merge_kernel<<<dim3((2 * S_TOT * 64) / 256), 256, 0, stream>>>(prt, mlw, awb);

    gemm_mfma_kernel<2><<<dim3(S_TOT / 128, CIN / 128, 2), 256, 0, stream>>>(
        wob, awb, out, b_out, HID, 0L, (long)S_TOT * HID);
}

// Round 14
// 120.054 us; speedup vs baseline: 1.6133x; 1.0189x over previous
//
#include <hip/hip_runtime.h>
#include <cmath>

#define S_TOT 4096
#define CIN   256
#define HID   512
#define NHEAD 8
#define DIMH  64

typedef __attribute__((ext_vector_type(8))) short bf16x8;
typedef __attribute__((ext_vector_type(4))) float f32x4;
typedef __attribute__((ext_vector_type(16))) float f32x16;
typedef __attribute__((address_space(1))) const void gv_t;
typedef __attribute__((address_space(3))) void lv_t;

__device__ __forceinline__ ushort f2bf(float f) {
    union { float f; unsigned u; } v; v.f = f;
    unsigned r = (v.u + 0x7FFFu + ((v.u >> 16) & 1u)) >> 16;
    return (ushort)r;
}

__device__ __forceinline__ float bf2f(ushort u) {
    union { unsigned u; float f; } v; v.u = ((unsigned)u) << 16; return v.f;
}

__device__ __forceinline__ float exp2_fast(float x) {
    float r; asm("v_exp_f32 %0, %1" : "=v"(r) : "v"(x)); return r;
}

__device__ __forceinline__ unsigned cvt_pk_bf16(float lo, float hi) {
    unsigned r; asm("v_cvt_pk_bf16_f32 %0, %1, %2" : "=v"(r) : "v"(lo), "v"(hi)); return r;
}

// 0.125 (1/sqrt(64)) * log2(e): folds softmax base-2 conversion into Q.
#define QSCALE 0.18033688011112042f

// ---------------------------------------------------------------------------
// Fused prologue: w_qkv cast (blocks 0..383), w_out cast (384..511),
// x transpose-cast (512..1023).
// ---------------------------------------------------------------------------
__global__ __launch_bounds__(256)
void prologue_kernel(const float* __restrict__ w_qkv, const float* __restrict__ w_out,
                     const float* __restrict__ x, ushort* __restrict__ wqb,
                     ushort* __restrict__ wob, ushort* __restrict__ xt) {
    __shared__ float tb[64][65];
    const int bid = blockIdx.x, t = threadIdx.x;
    if (bid < 512) {
        const float* src = (bid < 384) ? w_qkv : w_out;
        ushort* dst = (bid < 384) ? wqb : wob;
        const long i = ((long)(bid < 384 ? bid : bid - 384) * 256 + t) * 4;
        float4 v = *(const float4*)&src[i];
        ushort4 p;
        p.x = f2bf(v.x); p.y = f2bf(v.y); p.z = f2bf(v.z); p.w = f2bf(v.w);
        *(ushort4*)&dst[i] = p;
        return;
    }
    const int xb_ = bid - 512;              // [0,512): (s0/64) + 64*(c0/64 + 4*z)
    const int sx = xb_ & 63, rest = xb_ >> 6;
    const int cy = rest & 3, cz = rest >> 2;
    const int s0 = sx * 64, c0 = cy * 64;
    const long xb = (long)cz * CIN * S_TOT;
    #pragma unroll
    for (int i = 0; i < 16; ++i) {
        int idx = t + i * 256;
        int c = idx >> 6, s = idx & 63;
        tb[c][s] = x[xb + (long)(c0 + c) * S_TOT + s0 + s];
    }
    __syncthreads();
    const long ob = (long)cz * S_TOT * CIN;
    const int s = t >> 2, cq = (t & 3) * 16;
    #pragma unroll
    for (int j = 0; j < 4; ++j) {
        ushort4 pk;
        pk.x = f2bf(tb[cq + j * 4 + 0][s]);
        pk.y = f2bf(tb[cq + j * 4 + 1][s]);
        pk.z = f2bf(tb[cq + j * 4 + 2][s]);
        pk.w = f2bf(tb[cq + j * 4 + 3][s]);
        *(ushort4*)&xt[ob + (long)(s0 + s) * CIN + c0 + cq + j * 4] = pk;
    }
}

// ---------------------------------------------------------------------------
// Fused QKV GEMM (one launch, 768 blocks, runtime block-uniform mode):
//  blocks [0,512):  mode 0 — A=xt (s rows), B=w_qkv[0:1024] -> q (QSCALE) / k
//  blocks [512,768): mode 1 — A=w_qkv[1024:1536], B=xt -> v [bh][d][s'] with
//                    key bits 2<->3 swapped per 16-key group.
// Kdim = 256 for both.
// ---------------------------------------------------------------------------
__global__ __launch_bounds__(256)
void gemm_qkv_kernel(const ushort* __restrict__ xt, const ushort* __restrict__ wqb,
                     ushort* __restrict__ qkws, ushort* __restrict__ vws) {
    __shared__ __attribute__((aligned(16))) ushort Abuf[128 * 64];
    __shared__ __attribute__((aligned(16))) ushort Bbuf[128 * 64];
    const int t = threadIdx.x, lane = t & 63;
    const int l15 = lane & 15, g = lane >> 4;
    const int wid = t >> 6, wr = wid >> 1, wc = wid & 1;

    const int bid = blockIdx.x;
    int mode, bx, by, bz;
    if (bid < 512) { mode = 0; bx = bid & 7;  by = (bid >> 3) & 31; bz = bid >> 8; }
    else { const int id = bid - 512; mode = 1; bx = id & 31; by = (id >> 5) & 3; bz = id >> 7; }
    const int am0 = by * 128, bn0 = bx * 128;
    const ushort* Ag = (mode == 0) ? (xt + (long)bz * S_TOT * CIN) : (wqb + (long)1024 * CIN);
    const ushort* Bg = (mode == 0) ? wqb : (xt + (long)bz * S_TOT * CIN);

    f32x4 acc[4][4];
    #pragma unroll
    for (int i = 0; i < 4; ++i)
        #pragma unroll
        for (int j = 0; j < 4; ++j)
            acc[i][j] = (f32x4){0.f, 0.f, 0.f, 0.f};

    for (int k0 = 0; k0 < CIN; k0 += 64) {
        __syncthreads();
        #pragma unroll
        for (int i = 0; i < 4; ++i) {
            const int chunk = t + i * 256;
            const int row = chunk >> 3, sl = chunk & 7;
            const ushort* srcA = Ag + (long)(am0 + row) * CIN + k0 + ((sl ^ (row & 7)) << 3);
            __builtin_amdgcn_global_load_lds((gv_t*)srcA,
                (lv_t*)((char*)Abuf + (i * 256 + (t & ~63)) * 16), 16, 0, 0);
            const ushort* srcB = Bg + (long)(bn0 + row) * CIN + k0 + ((sl ^ (row & 7)) << 3);
            __builtin_amdgcn_global_load_lds((gv_t*)srcB,
                (lv_t*)((char*)Bbuf + (i * 256 + (t & ~63)) * 16), 16, 0, 0);
        }
        asm volatile("s_waitcnt vmcnt(0)" ::: "memory");
        __syncthreads();

        bf16x8 bfr[4][2];
        #pragma unroll
        for (int fn = 0; fn < 4; ++fn) {
            const int row = wc * 64 + fn * 16 + l15;
            #pragma unroll
            for (int hf = 0; hf < 2; ++hf)
                bfr[fn][hf] = *(const bf16x8*)((const char*)Bbuf + row * 128
                                + (((hf * 4 + g) ^ (row & 7)) << 4));
        }
        #pragma unroll
        for (int fm = 0; fm < 4; ++fm) {
            const int row = wr * 64 + fm * 16 + l15;
            const bf16x8 a0 = *(const bf16x8*)((const char*)Abuf + row * 128
                                + (((g) ^ (row & 7)) << 4));
            const bf16x8 a1 = *(const bf16x8*)((const char*)Abuf + row * 128
                                + (((4 + g) ^ (row & 7)) << 4));
            #pragma unroll
            for (int fn = 0; fn < 4; ++fn) {
                acc[fm][fn] = __builtin_amdgcn_mfma_f32_16x16x32_bf16(a0, bfr[fn][0], acc[fm][fn], 0, 0, 0);
                acc[fm][fn] = __builtin_amdgcn_mfma_f32_16x16x32_bf16(a1, bfr[fn][1], acc[fm][fn], 0, 0, 0);
            }
        }
    }

    #pragma unroll
    for (int fm = 0; fm < 4; ++fm)
        #pragma unroll
        for (int fn = 0; fn < 4; ++fn)
            #pragma unroll
            for (int r = 0; r < 4; ++r) {
                const int ar = am0 + wr * 64 + fm * 16 + g * 4 + r;
                const int bc = bn0 + wc * 64 + fn * 16 + l15;
                if (mode == 0) {
                    const int which = bc >> 9, h = (bc >> 6) & 7, d = bc & 63;
                    const float scl = (which == 0) ? QSCALE : 1.0f;
                    qkws[(long)which * 4194304 + (((long)(bz * NHEAD + h)) * S_TOT + ar) * DIMH + d]
                        = f2bf(acc[fm][fn][r] * scl);
                } else {
                    const int h = ar >> 6, d = ar & 63;
                    const int jm = bc & 15;
                    const int pjm = (jm & 3) | ((jm & 4) << 1) | ((jm & 8) >> 1);
                    const int pc = (bc & ~15) | pjm;
                    vws[(((long)(bz * NHEAD + h)) * DIMH + d) * S_TOT + pc] = f2bf(acc[fm][fn][r]);
                }
            }
}

// ---------------------------------------------------------------------------
// Flash attention, 32x32x16, key-split x2 — EXACT round-9/12 version
// (measured 83.5-83.9 us, FETCH 70.7 MB, WRITE 19.5 MB, conflicts 0).
// ---------------------------------------------------------------------------
__global__ __launch_bounds__(256, 4)
void attn_mfma_kernel(const ushort* __restrict__ qg, const ushort* __restrict__ kg,
                      const ushort* __restrict__ vg, ushort* __restrict__ pout,
                      float2* __restrict__ mlout) {
    __shared__ __attribute__((aligned(16))) ushort kbuf[2][64 * 64];
    __shared__ __attribute__((aligned(16))) ushort vbuf[2][64 * 64];

    const int t = threadIdx.x;
    const int lane = t & 63, wid = t >> 6;          // wid 0..3
    const int l31 = lane & 31, h = lane >> 5;
    const int head = blockIdx.y;
    const int b = blockIdx.z >> 1, sp = blockIdx.z & 1;
    const int bh = b * NHEAD + head;
    const int qrow0 = blockIdx.x * 128 + wid * 32;
    const long kbase = (long)sp * (S_TOT / 2);

    const int sw_lo = (l31 ^ (l31 >> 3)) & 7;
    const int sw_hi = sw_lo ^ 4;

    // Q B-fragments: col q = l31, k(d) = ds*16 + 8h + j  (pre-scaled)
    const ushort* qp = qg + ((long)bh * S_TOT + qrow0 + l31) * DIMH + h * 8;
    bf16x8 qfr[4];
    #pragma unroll
    for (int ds = 0; ds < 4; ++ds) qfr[ds] = *(const bf16x8*)(qp + ds * 16);

    f32x16 oacc0 = {}, oacc1 = {};
    f32x16 bias16 = {};                 // -(accumulated rescale) broadcast
    float nmr = 0.f, lrun = 0.f;        // per-lane, q = l31 domain

    const long kg_base = (long)bh * S_TOT * DIMH;
    const long vg_base = (long)bh * DIMH * S_TOT;
    const int sl = lane & 7, sr = lane >> 3;

    auto STAGE = [&](int buf, long key0) {
        #pragma unroll
        for (int c = 0; c < 2; ++c) {
            const int row = wid * 16 + c * 8 + sr;          // row>>3 = wid*2+c
            const int sz = (sl ^ sr ^ (wid * 2 + c)) & 7;   // src chunk for slot sl
            char* kdst = (char*)(&kbuf[buf][0]) + wid * 2048 + c * 1024;
            char* vdst = (char*)(&vbuf[buf][0]) + wid * 2048 + c * 1024;
            const char* srcK = (const char*)(kg + kg_base + (key0 + row) * DIMH) + (sz << 4);
            __builtin_amdgcn_global_load_lds((gv_t*)srcK, (lv_t*)kdst, 16, 0, 0);
            const char* srcV = (const char*)(vg + vg_base + (long)row * S_TOT + key0) + (sz << 4);
            __builtin_amdgcn_global_load_lds((gv_t*)srcV, (lv_t*)vdst, 16, 0, 0);
        }
    };

    STAGE(0, kbase);
    asm volatile("s_waitcnt vmcnt(0)" ::: "memory");
    __syncthreads();

    const int NT = (S_TOT / 2) / 64;   // 32 tiles per split
    for (int kt0 = 0; kt0 < NT; ++kt0) {
        const int cur = kt0 & 1;
        if (kt0 + 1 < NT) STAGE(cur ^ 1, kbase + (long)(kt0 + 1) * 64);

        const char* kb_ = (const char*)(&kbuf[cur][0]);
        const char* vb_ = (const char*)(&vbuf[cur][0]);

        // --- S^T = K Q^T + bias: lane q=l31; key = 32kg + (r&3)+8(r>>2)+4h
        f32x16 s0, s1;
        __builtin_amdgcn_s_setprio(1);
        {
            const bf16x8 kf0 = *(const bf16x8*)(kb_ + l31 * 128 + ((h ^ sw_lo) << 4));
            const bf16x8 kf1 = *(const bf16x8*)(kb_ + 4096 + l31 * 128 + ((h ^ sw_hi) << 4));
            s0 = __builtin_amdgcn_mfma_f32_32x32x16_bf16(kf0, qfr[0], bias16, 0, 0, 0);
            s1 = __builtin_amdgcn_mfma_f32_32x32x16_bf16(kf1, qfr[0], bias16, 0, 0, 0);
        }
        #pragma unroll
        for (int ds = 1; ds < 4; ++ds) {
            const bf16x8 kf0 = *(const bf16x8*)(kb_ + l31 * 128 + (((2 * ds + h) ^ sw_lo) << 4));
            const bf16x8 kf1 = *(const bf16x8*)(kb_ + 4096 + l31 * 128 + (((2 * ds + h) ^ sw_hi) << 4));
            s0 = __builtin_amdgcn_mfma_f32_32x32x16_bf16(kf0, qfr[ds], s0, 0, 0, 0);
            s1 = __builtin_amdgcn_mfma_f32_32x32x16_bf16(kf1, qfr[ds], s1, 0, 0, 0);
        }
        __builtin_amdgcn_s_setprio(0);

        // --- exp + pack P directly (V key order pre-swapped in global) ---
        bf16x8 pf0, pf1, pf2, pf3;
        {
            float e[16];
            #pragma unroll
            for (int r = 0; r < 16; ++r) e[r] = exp2_fast(s0[r]);
            #pragma unroll
            for (int r = 0; r < 16; ++r) lrun += e[r];
            union { unsigned u[4]; bf16x8 v; } A_, B_;
            #pragma unroll
            for (int w = 0; w < 4; ++w) A_.u[w] = cvt_pk_bf16(e[2 * w], e[2 * w + 1]);
            #pragma unroll
            for (int w = 0; w < 4; ++w) B_.u[w] = cvt_pk_bf16(e[8 + 2 * w], e[9 + 2 * w]);
            pf0 = A_.v; pf1 = B_.v;
        }
        {
            float e[16];
            #pragma unroll
            for (int r = 0; r < 16; ++r) e[r] = exp2_fast(s1[r]);
            #pragma unroll
            for (int r = 0; r < 16; ++r) lrun += e[r];
            union { unsigned u[4]; bf16x8 v; } A_, B_;
            #pragma unroll
            for (int w = 0; w < 4; ++w) A_.u[w] = cvt_pk_bf16(e[2 * w], e[2 * w + 1]);
            #pragma unroll
            for (int w = 0; w < 4; ++w) B_.u[w] = cvt_pk_bf16(e[8 + 2 * w], e[9 + 2 * w]);
            pf2 = A_.v; pf3 = B_.v;
        }

        // --- O += P V: A = P (regs), B = V (LDS [d][key']) ---
        __builtin_amdgcn_s_setprio(1);
        {
            const bf16x8 vf00 = *(const bf16x8*)(vb_ + l31 * 128 + ((h ^ sw_lo) << 4));
            const bf16x8 vf01 = *(const bf16x8*)(vb_ + 4096 + l31 * 128 + ((h ^ sw_hi) << 4));
            oacc0 = __builtin_amdgcn_mfma_f32_32x32x16_bf16(pf0, vf00, oacc0, 0, 0, 0);
            oacc1 = __builtin_amdgcn_mfma_f32_32x32x16_bf16(pf0, vf01, oacc1, 0, 0, 0);
            const bf16x8 vf10 = *(const bf16x8*)(vb_ + l31 * 128 + (((2 + h) ^ sw_lo) << 4));
            const bf16x8 vf11 = *(const bf16x8*)(vb_ + 4096 + l31 * 128 + (((2 + h) ^ sw_hi) << 4));
            oacc0 = __builtin_amdgcn_mfma_f32_32x32x16_bf16(pf1, vf10, oacc0, 0, 0, 0);
            oacc1 = __builtin_amdgcn_mfma_f32_32x32x16_bf16(pf1, vf11, oacc1, 0, 0, 0);
            const bf16x8 vf20 = *(const bf16x8*)(vb_ + l31 * 128 + (((4 + h) ^ sw_lo) << 4));
            const bf16x8 vf21 = *(const bf16x8*)(vb_ + 4096 + l31 * 128 + (((4 + h) ^ sw_hi) << 4));
            oacc0 = __builtin_amdgcn_mfma_f32_32x32x16_bf16(pf2, vf20, oacc0, 0, 0, 0);
            oacc1 = __builtin_amdgcn_mfma_f32_32x32x16_bf16(pf2, vf21, oacc1, 0, 0, 0);
            const bf16x8 vf30 = *(const bf16x8*)(vb_ + l31 * 128 + (((6 + h) ^ sw_lo) << 4));
            const bf16x8 vf31 = *(const bf16x8*)(vb_ + 4096 + l31 * 128 + (((6 + h) ^ sw_hi) << 4));
            oacc0 = __builtin_amdgcn_mfma_f32_32x32x16_bf16(pf3, vf30, oacc0, 0, 0, 0);
            oacc1 = __builtin_amdgcn_mfma_f32_32x32x16_bf16(pf3, vf31, oacc1, 0, 0, 0);
        }
        __builtin_amdgcn_s_setprio(0);

        // --- rare uniform overflow guard (keeps fp32/bf16 in range for any data)
        if (__any(lrun > 1.6777216e7f)) {       // 2^24
            const float sc = 5.9604644775390625e-8f;   // 2^-24
            lrun *= sc;
            #pragma unroll
            for (int r = 0; r < 16; ++r) { oacc0[r] *= sc; oacc1[r] *= sc; }
            nmr -= 24.0f;
            #pragma unroll
            for (int r = 0; r < 16; ++r) bias16[r] = nmr;
        }

        asm volatile("s_waitcnt vmcnt(0)" ::: "memory");
        __syncthreads();
    }

    // epilogue: write unnormalized partial O (bf16) + per-q (m, l) fp32
    lrun += __shfl_xor(lrun, 32, 64);                 // full sum per q=l31
    const long pbase = (((long)sp * 2 + b) * S_TOT) * HID;
    #pragma unroll
    for (int r = 0; r < 16; ++r) {
        const int q = (r & 3) + 8 * (r >> 2) + 4 * h;
        const long off = pbase + (long)(qrow0 + q) * HID + head * 64 + l31;
        pout[off]      = f2bf(oacc0[r]);
        pout[off + 32] = f2bf(oacc1[r]);
    }
    if (h == 0)
        mlout[((long)sp * 2 * NHEAD * S_TOT) + (long)bh * S_TOT + qrow0 + l31]
            = make_float2(-nmr, lrun);
}

// ---------------------------------------------------------------------------
// Output projection with INLINE key-split merge in the B-staging path:
// B[s][hd] = (w0*O0[s][hd] + w1*O1[s][hd]) * inv, computed per 16B chunk and
// ds_write'n to the exact LDS image global_load_lds would produce (chunk
// ci = i*256+t at offset ci*16, source slot sl^(row&7)). Per K-step the head
// h = k0/64 is constant, so (w0,w1,inv) depend only on row s.
// A = w_out via global_load_lds (unchanged). D[o][s] fp32 + bias.
// ---------------------------------------------------------------------------
__global__ __launch_bounds__(256)
void gemm_out_merge_kernel(const ushort* __restrict__ Ag, const ushort* __restrict__ part,
                           const float2* __restrict__ ml, float* __restrict__ outp,
                           const float* __restrict__ bias) {
    __shared__ __attribute__((aligned(16))) ushort Abuf[128 * 64];
    __shared__ __attribute__((aligned(16))) ushort Bbuf[128 * 64];
    const int t = threadIdx.x, lane = t & 63;
    const int l15 = lane & 15, g = lane >> 4;
    const int wid = t >> 6, wr = wid >> 1, wc = wid & 1;
    const int bz = blockIdx.z;
    const int am0 = blockIdx.y * 128, bn0 = blockIdx.x * 128;
    const long PSP = (long)2 * S_TOT * HID;
    const long MLSP = (long)2 * NHEAD * S_TOT;

    f32x4 acc[4][4];
    #pragma unroll
    for (int i = 0; i < 4; ++i)
        #pragma unroll
        for (int j = 0; j < 4; ++j)
            acc[i][j] = (f32x4){0.f, 0.f, 0.f, 0.f};

    for (int k0 = 0; k0 < HID; k0 += 64) {
        __syncthreads();
        // A staging (w_out, shared across batch)
        #pragma unroll
        for (int i = 0; i < 4; ++i) {
            const int chunk = t + i * 256;
            const int row = chunk >> 3, sl = chunk & 7;
            const ushort* srcA = Ag + (long)(am0 + row) * HID + k0 + ((sl ^ (row & 7)) << 3);
            __builtin_amdgcn_global_load_lds((gv_t*)srcA,
                (lv_t*)((char*)Abuf + (i * 256 + (t & ~63)) * 16), 16, 0, 0);
        }
        // B staging: inline merge of the two key-split partials
        const int h = k0 >> 6;
        const long mlb = (long)(bz * NHEAD + h) * S_TOT;
        #pragma unroll
        for (int i = 0; i < 4; ++i) {
            const int chunk = t + i * 256;
            const int row = chunk >> 3, sl = chunk & 7;
            const int s = bn0 + row;
            const float2 ml0 = ml[mlb + s];
            const float2 ml1 = ml[MLSP + mlb + s];
            const float m = fmaxf(ml0.x, ml1.x);
            const float w0 = exp2_fast(ml0.x - m), w1 = exp2_fast(ml1.x - m);
            const float inv = 1.0f / (w0 * ml0.y + w1 * ml1.y);
            const long off = ((long)bz * S_TOT + s) * HID + k0 + ((sl ^ (row & 7)) << 3);
            const bf16x8 p0 = *(const bf16x8*)&part[off];
            const bf16x8 p1 = *(const bf16x8*)&part[PSP + off];
            union { unsigned u[4]; bf16x8 v; } M_;
            #pragma unroll
            for (int w = 0; w < 4; ++w) {
                const float e0 = (w0 * bf2f((ushort)p0[2 * w])     + w1 * bf2f((ushort)p1[2 * w]))     * inv;
                const float e1 = (w0 * bf2f((ushort)p0[2 * w + 1]) + w1 * bf2f((ushort)p1[2 * w + 1])) * inv;
                M_.u[w] = cvt_pk_bf16(e0, e1);
            }
            *(bf16x8*)((char*)Bbuf + (long)chunk * 16) = M_.v;
        }
        asm volatile("s_waitcnt vmcnt(0)" ::: "memory");
        __syncthreads();

        bf16x8 bfr[4][2];
        #pragma unroll
        for (int fn = 0; fn < 4; ++fn) {
            const int row = wc * 64 + fn * 16 + l15;
            #pragma unroll
            for (int hf = 0; hf < 2; ++hf)
                bfr[fn][hf] = *(const bf16x8*)((const char*)Bbuf + row * 128
                                + (((hf * 4 + g) ^ (row & 7)) << 4));
        }
        #pragma unroll
        for (int fm = 0; fm < 4; ++fm) {
            const int row = wr * 64 + fm * 16 + l15;
            const bf16x8 a0 = *(const bf16x8*)((const char*)Abuf + row * 128
                                + (((g) ^ (row & 7)) << 4));
            const bf16x8 a1 = *(const bf16x8*)((const char*)Abuf + row * 128
                                + (((4 + g) ^ (row & 7)) << 4));
            #pragma unroll
            for (int fn = 0; fn < 4; ++fn) {
                acc[fm][fn] = __builtin_amdgcn_mfma_f32_16x16x32_bf16(a0, bfr[fn][0], acc[fm][fn], 0, 0, 0);
                acc[fm][fn] = __builtin_amdgcn_mfma_f32_16x16x32_bf16(a1, bfr[fn][1], acc[fm][fn], 0, 0, 0);
            }
        }
    }

    #pragma unroll
    for (int fm = 0; fm < 4; ++fm)
        #pragma unroll
        for (int fn = 0; fn < 4; ++fn)
            #pragma unroll
            for (int r = 0; r < 4; ++r) {
                const int ar = am0 + wr * 64 + fm * 16 + g * 4 + r;
                const int bc = bn0 + wc * 64 + fn * 16 + l15;
                outp[((long)bz * CIN + ar) * S_TOT + bc] = acc[fm][fn][r] + bias[ar];
            }
}

// ---------------------------------------------------------------------------
extern "C" void kernel_launch(void* const* d_in, const int* in_sizes, int n_in,
                              void* d_out, int out_size, void* d_ws, size_t ws_size,
                              hipStream_t stream) {
    const float* x     = (const float*)d_in[0];
    const float* w_qkv = (const float*)d_in[1];
    const float* w_out = (const float*)d_in[2];
    const float* b_out = (const float*)d_in[3];
    float* out = (float*)d_out;

    const long PERQKV = (long)2 * NHEAD * S_TOT * DIMH;   // 4,194,304
    ushort* qws = (ushort*)d_ws;
    ushort* kws = qws + PERQKV;
    ushort* vws = kws + PERQKV;
    ushort* xt  = vws + PERQKV;                           // 2*4096*256
    ushort* wqb = xt + (long)2 * S_TOT * CIN;             // 1536*256
    ushort* wob = wqb + (long)3 * HID * CIN;              // 256*512
    ushort* awb = wob + (long)CIN * HID;                  // (unused, layout kept)
    ushort* prt = awb + (long)2 * S_TOT * HID;            // 2 splits * 2*4096*512
    float2* mlw = (float2*)(prt + (long)4 * S_TOT * HID); // 2*16*4096 float2

    prologue_kernel<<<dim3(1024), 256, 0, stream>>>(w_qkv, w_out, x, wqb, wob, xt);

    gemm_qkv_kernel<<<dim3(768), 256, 0, stream>>>(xt, wqb, qws, vws);

    attn_mfma_kernel<<<dim3(S_TOT / 128, NHEAD, 4), 256, 0, stream>>>(
        qws, kws, vws, prt, mlw);

    gemm_out_merge_kernel<<<dim3(S_TOT / 128, CIN / 128, 2), 256, 0, stream>>>(
        wob, prt, mlw, out, b_out);
}